// Round 1
// baseline (138.841 us; speedup 1.0000x reference)
//
#include <hip/hip_runtime.h>
#include <cmath>

#define P 5
#define LBV 0.0f
#define UBV 0.5f
#define RFV 1.03f
#define ALPHA 0.1f
#define OMEGA 0.05f
#define BETA 0.05f
#define MU 0.01f
#define NTHR 256

// One thread per sample. Only layer k=3 contributes to the output (the
// reference loop re-consumes the ORIGINAL x1/x2 each iteration and only the
// last iteration's wealth/curr_cov survive).
__global__ __launch_bounds__(NTHR) void portfolio_kernel(
    const float* __restrict__ x1,
    const float* __restrict__ x2,
    const float* __restrict__ eps,
    const float* __restrict__ W,
    float* __restrict__ out, int B)
{
    __shared__ float sW[3 * P * P];          // W[3], 75 floats
    __shared__ float sX2[NTHR * P * P];      // 25.6 KB
    __shared__ float sE[NTHR * P];           // 5 KB

    const int tid = threadIdx.x;
    const int b0  = blockIdx.x * NTHR;

    if (tid < 3 * P * P) sW[tid] = W[3 * 3 * P * P + tid];

    // Coalesced staging: linear copy of this block's x2 rows and eps[3] rows.
    const float* gx2 = x2 + (size_t)b0 * (P * P);
    #pragma unroll
    for (int i = 0; i < P * P; ++i)
        sX2[i * NTHR + tid] = gx2[i * NTHR + tid];

    const float* ge = eps + (size_t)3 * B * P + (size_t)b0 * P;
    #pragma unroll
    for (int i = 0; i < P; ++i)
        sE[i * NTHR + tid] = ge[i * NTHR + tid];

    __syncthreads();

    float* row = &sX2[tid * (P * P)];        // this sample's x2 row (stride 25 -> conflict-free)
    float e[P];
    #pragma unroll
    for (int j = 0; j < P; ++j) e[j] = sE[tid * P + j];

    // Ce[i] = sum_j x2[i][j] * eps[j]
    float Ce[P];
    #pragma unroll
    for (int i = 0; i < P; ++i) {
        float s = 0.0f;
        #pragma unroll
        for (int j = 0; j < P; ++j) s = fmaf(row[i * P + j], e[j], s);
        Ce[i] = s;
    }

    float R[P], h[P];
    #pragma unroll
    for (int i = 0; i < P; ++i) { R[i] = MU + Ce[i]; h[i] = R[i]; }

    // 3 bias-free Linear(5,5) + tanh:  h_i = tanh(sum_j h_j * W[l][i][j])
    #pragma unroll
    for (int l = 0; l < 3; ++l) {
        float hn[P];
        #pragma unroll
        for (int i = 0; i < P; ++i) {
            float s = 0.0f;
            #pragma unroll
            for (int j = 0; j < P; ++j) s = fmaf(h[j], sW[l * P * P + i * P + j], s);
            hn[i] = tanhf(s);
        }
        #pragma unroll
        for (int i = 0; i < P; ++i) h[i] = hn[i];
    }

    // softmax over P
    float m = h[0];
    #pragma unroll
    for (int i = 1; i < P; ++i) m = fmaxf(m, h[i]);
    float w[P], ssum = 0.0f;
    #pragma unroll
    for (int i = 0; i < P; ++i) { w[i] = expf(h[i] - m); ssum += w[i]; }
    #pragma unroll
    for (int i = 0; i < P; ++i) w[i] /= ssum;

    // water-filling rebalance, exact reference semantics (8 iters, freeze on done)
    float oldv[P], nw[P];
    #pragma unroll
    for (int i = 0; i < P; ++i) {
        oldv[i] = w[i];
        nw[i]   = fminf(fmaxf(w[i], LBV), UBV);
    }
    bool done = false;
    #pragma unroll
    for (int it = 0; it < 8; ++it) {
        float leftover = 0.0f;
        #pragma unroll
        for (int i = 0; i < P; ++i) leftover += oldv[i] - nw[i];
        float mk[P], msum = 0.0f;
        #pragma unroll
        for (int i = 0; i < P; ++i) {
            mk[i] = (nw[i] != UBV) ? nw[i] : 0.0f;
            msum += mk[i];
        }
        float n2[P];
        #pragma unroll
        for (int i = 0; i < P; ++i)
            n2[i] = nw[i] + leftover * mk[i] / msum;
        bool cont = false;
        #pragma unroll
        for (int i = 0; i < P; ++i) cont = cont || (n2[i] > UBV);
        if (!done) {
            #pragma unroll
            for (int i = 0; i < P; ++i) {
                oldv[i] = n2[i];
                nw[i]   = cont ? fminf(fmaxf(n2[i], LBV), UBV) : n2[i];
            }
        }
        done = done || (!cont);
    }

    // wealth = x1 * RF * sum_i nw[i] * (1 + R[i])
    float x1v = x1[b0 + tid];
    float ws = 0.0f;
    #pragma unroll
    for (int i = 0; i < P; ++i) ws = fmaf(nw[i], 1.0f + R[i], ws);
    out[b0 + tid] = x1v * ws * RFV;

    // curr_cov[i][j] = OMEGA + ALPHA*x2[i][j] + BETA*Ce[j]^2  (in-place into own LDS row)
    float ce2[P];
    #pragma unroll
    for (int j = 0; j < P; ++j) ce2[j] = Ce[j] * Ce[j];
    #pragma unroll
    for (int i = 0; i < P; ++i) {
        #pragma unroll
        for (int j = 0; j < P; ++j) {
            float v = row[i * P + j];
            row[i * P + j] = fmaf(BETA, ce2[j], fmaf(ALPHA, v, OMEGA));
        }
    }

    __syncthreads();

    // coalesced cov store
    float* gout = out + B + (size_t)b0 * (P * P);
    #pragma unroll
    for (int i = 0; i < P * P; ++i)
        gout[i * NTHR + tid] = sX2[i * NTHR + tid];
}

extern "C" void kernel_launch(void* const* d_in, const int* in_sizes, int n_in,
                              void* d_out, int out_size, void* d_ws, size_t ws_size,
                              hipStream_t stream) {
    const float* x1  = (const float*)d_in[0];
    const float* x2  = (const float*)d_in[1];
    const float* eps = (const float*)d_in[2];
    const float* W   = (const float*)d_in[3];
    float* out = (float*)d_out;
    const int B = in_sizes[0];           // 524288
    const int blocks = B / NTHR;         // B divisible by 256
    portfolio_kernel<<<blocks, NTHR, 0, stream>>>(x1, x2, eps, W, out, B);
}

// Round 2
// 134.481 us; speedup vs baseline: 1.0324x; 1.0324x over previous
//
#include <hip/hip_runtime.h>
#include <cmath>

#define P 5
#define LBV 0.0f
#define UBV 0.5f
#define RFV 1.03f
#define ALPHA 0.1f
#define OMEGA 0.05f
#define BETA 0.05f
#define MU 0.01f
#define NTHR 256

// tanh via HW v_exp_f32 + v_rcp_f32. For |x| large, exp(-2|x|)->0 => r->1.
__device__ __forceinline__ float fast_tanh(float x) {
    float ax = fabsf(x);
    float t  = __expf(-2.0f * ax);                       // v_mul + v_exp_f32
    float r  = (1.0f - t) * __builtin_amdgcn_rcpf(1.0f + t);
    return copysignf(r, x);                              // v_bfi
}

// One thread per sample. Only layer k=3 contributes to the output (the
// reference loop re-consumes the ORIGINAL x1/x2 each iteration and only the
// last iteration's wealth/curr_cov survive).
__global__ __launch_bounds__(NTHR) void portfolio_kernel(
    const float* __restrict__ x1,
    const float* __restrict__ x2,
    const float* __restrict__ eps,
    const float* __restrict__ W,
    float* __restrict__ out, int B)
{
    __shared__ float sW[3 * P * P];          // W[3], 75 floats
    __shared__ float sX2[NTHR * P * P];      // 25.6 KB
    __shared__ float sE[NTHR * P];           // 5 KB

    const int tid = threadIdx.x;
    const int b0  = blockIdx.x * NTHR;

    if (tid < 3 * P * P) sW[tid] = W[3 * 3 * P * P + tid];

    // Coalesced staging: linear copy of this block's x2 rows and eps[3] rows.
    const float* gx2 = x2 + (size_t)b0 * (P * P);
    #pragma unroll
    for (int i = 0; i < P * P; ++i)
        sX2[i * NTHR + tid] = gx2[i * NTHR + tid];

    const float* ge = eps + (size_t)3 * B * P + (size_t)b0 * P;
    #pragma unroll
    for (int i = 0; i < P; ++i)
        sE[i * NTHR + tid] = ge[i * NTHR + tid];

    __syncthreads();

    float* row = &sX2[tid * (P * P)];        // stride 25 between lanes -> 2-way bank alias (free)
    // Pull the whole x2 row into registers once (ds_read_b128 x6); reused in epilogue.
    float r2[P * P];
    #pragma unroll
    for (int i = 0; i < P * P; ++i) r2[i] = row[i];

    float e[P];
    #pragma unroll
    for (int j = 0; j < P; ++j) e[j] = sE[tid * P + j];

    // Ce[i] = sum_j x2[i][j] * eps[j]
    float Ce[P];
    #pragma unroll
    for (int i = 0; i < P; ++i) {
        float s = 0.0f;
        #pragma unroll
        for (int j = 0; j < P; ++j) s = fmaf(r2[i * P + j], e[j], s);
        Ce[i] = s;
    }

    float R[P], h[P];
    #pragma unroll
    for (int i = 0; i < P; ++i) { R[i] = MU + Ce[i]; h[i] = R[i]; }

    // 3 bias-free Linear(5,5) + tanh:  h_i = tanh(sum_j h_j * W[l][i][j])
    #pragma unroll
    for (int l = 0; l < 3; ++l) {
        float hn[P];
        #pragma unroll
        for (int i = 0; i < P; ++i) {
            float s = 0.0f;
            #pragma unroll
            for (int j = 0; j < P; ++j) s = fmaf(h[j], sW[l * P * P + i * P + j], s);
            hn[i] = fast_tanh(s);
        }
        #pragma unroll
        for (int i = 0; i < P; ++i) h[i] = hn[i];
    }

    // softmax over P — h in (-1,1) so no max-subtraction needed
    float w[P], ssum = 0.0f;
    #pragma unroll
    for (int i = 0; i < P; ++i) { w[i] = __expf(h[i]); ssum += w[i]; }
    float rs = __builtin_amdgcn_rcpf(ssum);
    #pragma unroll
    for (int i = 0; i < P; ++i) w[i] *= rs;

    // water-filling rebalance; break==freeze (matches reference done semantics)
    float oldv[P], nw[P];
    #pragma unroll
    for (int i = 0; i < P; ++i) {
        oldv[i] = w[i];
        nw[i]   = fminf(fmaxf(w[i], LBV), UBV);
    }
    #pragma unroll
    for (int it = 0; it < 8; ++it) {
        float leftover = 0.0f;
        #pragma unroll
        for (int i = 0; i < P; ++i) leftover += oldv[i] - nw[i];
        float mk[P], msum = 0.0f;
        #pragma unroll
        for (int i = 0; i < P; ++i) {
            mk[i] = (nw[i] != UBV) ? nw[i] : 0.0f;
            msum += mk[i];
        }
        float scale = leftover * __builtin_amdgcn_rcpf(msum);
        float n2[P];
        #pragma unroll
        for (int i = 0; i < P; ++i) n2[i] = fmaf(scale, mk[i], nw[i]);
        bool cont = false;
        #pragma unroll
        for (int i = 0; i < P; ++i) cont = cont || (n2[i] > UBV);
        #pragma unroll
        for (int i = 0; i < P; ++i) {
            oldv[i] = n2[i];
            nw[i]   = cont ? fminf(fmaxf(n2[i], LBV), UBV) : n2[i];
        }
        if (!cont) break;                    // converged rows are frozen from here on
    }

    // wealth = x1 * RF * sum_i nw[i] * (1 + R[i])
    float x1v = x1[b0 + tid];
    float ws = 0.0f;
    #pragma unroll
    for (int i = 0; i < P; ++i) ws = fmaf(nw[i], 1.0f + R[i], ws);
    out[b0 + tid] = x1v * ws * RFV;

    // curr_cov[i][j] = OMEGA + ALPHA*x2[i][j] + BETA*Ce[j]^2 -> back into LDS row
    float ce2[P];
    #pragma unroll
    for (int j = 0; j < P; ++j) ce2[j] = Ce[j] * Ce[j];
    #pragma unroll
    for (int i = 0; i < P; ++i) {
        #pragma unroll
        for (int j = 0; j < P; ++j)
            row[i * P + j] = fmaf(BETA, ce2[j], fmaf(ALPHA, r2[i * P + j], OMEGA));
    }

    __syncthreads();

    // coalesced cov store
    float* gout = out + B + (size_t)b0 * (P * P);
    #pragma unroll
    for (int i = 0; i < P * P; ++i)
        gout[i * NTHR + tid] = sX2[i * NTHR + tid];
}

extern "C" void kernel_launch(void* const* d_in, const int* in_sizes, int n_in,
                              void* d_out, int out_size, void* d_ws, size_t ws_size,
                              hipStream_t stream) {
    const float* x1  = (const float*)d_in[0];
    const float* x2  = (const float*)d_in[1];
    const float* eps = (const float*)d_in[2];
    const float* W   = (const float*)d_in[3];
    float* out = (float*)d_out;
    const int B = in_sizes[0];           // 524288
    const int blocks = B / NTHR;
    portfolio_kernel<<<blocks, NTHR, 0, stream>>>(x1, x2, eps, W, out, B);
}